// Round 5
// baseline (5160.331 us; speedup 1.0000x reference)
//
#include <hip/hip_runtime.h>
#include <hip/hip_bf16.h>

#define TT  512
#define BB  256
#define IND 64
#define HH  512
#define OD  64
#define BBHH (BB * HH)
#define NSLOT 8      // h ring depth (slot = t & 7)
#define FSTRIDE 32   // ints per flag line (128B)
#define XSTR 133     // xch row stride in floats (133 % 32 = 5, coprime -> no bank conflicts)

typedef __bf16 v8bf  __attribute__((ext_vector_type(8)));
typedef float  v4f   __attribute__((ext_vector_type(4)));
typedef float  v16f  __attribute__((ext_vector_type(16)));

struct Params {
  const __bf16 *xb, *Wi0, *Wh0, *Wi1, *Wh1, *Wlin;
  const float  *bsum0, *bsum1, *blin;
  __bf16 *h0, *h1;          // NSLOT-deep ring buffers [NSLOT][BB*HH]
  int *flags;               // per-producer: [0..63]=L0, [64..191]=L1, [192..199]=lin
  float *out;               // [BB][TT*OD]
};

__device__ __forceinline__ float sigm(float x) { return 1.f / (1.f + __expf(-x)); }
__device__ __forceinline__ float tanh_fast(float x) {
  float e = __expf(2.f * x);
  return 1.f - 2.f / (e + 1.f);
}
__device__ __forceinline__ v4f mfma16(v8bf a, v8bf b, v4f c) {
  return __builtin_amdgcn_mfma_f32_16x16x32_bf16(a, b, c, 0, 0, 0);
}
__device__ __forceinline__ v16f mfma32(v8bf a, v8bf b, v16f c) {
  return __builtin_amdgcn_mfma_f32_32x32x16_bf16(a, b, c, 0, 0, 0);
}
__device__ __forceinline__ v8bf bc(v4f x) { return __builtin_bit_cast(v8bf, x); }

// Agent-scope (coherent at LLC) data movement — no fences needed.
__device__ __forceinline__ unsigned long long aload8(const unsigned long long* p) {
  return __hip_atomic_load(p, __ATOMIC_RELAXED, __HIP_MEMORY_SCOPE_AGENT);
}
__device__ __forceinline__ void astore8(unsigned long long* p, unsigned long long v) {
  __hip_atomic_store(p, v, __ATOMIC_RELAXED, __HIP_MEMORY_SCOPE_AGENT);
}
__device__ __forceinline__ void pollOne(const int* p, int target) {
  while (__hip_atomic_load(p, __ATOMIC_RELAXED, __HIP_MEMORY_SCOPE_AGENT) < target)
    __builtin_amdgcn_s_sleep(1);
}
__device__ __forceinline__ void drainAll() {
  asm volatile("s_waitcnt vmcnt(0)" ::: "memory");
  __syncthreads();
}
__device__ __forceinline__ void setFlag(int* f, int v) {
  if (threadIdx.x == 0)
    __hip_atomic_store(f, v, __ATOMIC_RELAXED, __HIP_MEMORY_SCOPE_AGENT);
}

// ---------------- prep: fp32 -> bf16, combined biases, zero states/flags -------
__global__ void __launch_bounds__(256) prep_kernel(
    const float* x, const float* Wi0, const float* Wh0, const float* bi0, const float* bh0,
    const float* Wi1, const float* Wh1, const float* bi1, const float* bh1, const float* Wlin,
    __bf16* xb, __bf16* Wi0b, __bf16* Wh0b, __bf16* Wi1b, __bf16* Wh1b, __bf16* Wlinb,
    float* bsum0, float* bsum1, __bf16* h0, __bf16* h1, int* flags) {
  size_t tid = (size_t)blockIdx.x * blockDim.x + threadIdx.x;
  size_t np  = (size_t)gridDim.x * blockDim.x;
  for (size_t i = tid; i < (size_t)TT * BB * IND; i += np) xb[i]    = (__bf16)x[i];
  for (size_t i = tid; i < (size_t)4 * HH * IND;  i += np) Wi0b[i]  = (__bf16)Wi0[i];
  for (size_t i = tid; i < (size_t)4 * HH * HH;   i += np) Wh0b[i]  = (__bf16)Wh0[i];
  for (size_t i = tid; i < (size_t)4 * HH * HH;   i += np) Wi1b[i]  = (__bf16)Wi1[i];
  for (size_t i = tid; i < (size_t)4 * HH * HH;   i += np) Wh1b[i]  = (__bf16)Wh1[i];
  for (size_t i = tid; i < (size_t)OD * HH;       i += np) Wlinb[i] = (__bf16)Wlin[i];
  for (size_t i = tid; i < (size_t)4 * HH; i += np) {
    bsum0[i] = bi0[i] + bh0[i];
    bsum1[i] = bi1[i] + bh1[i];
  }
  for (size_t i = tid; i < (size_t)NSLOT * BBHH; i += np) { h0[i] = (__bf16)0.f; h1[i] = (__bf16)0.f; }
  for (size_t i = tid; i < (size_t)200 * FSTRIDE; i += np) flags[i] = 0;
}

// ---------------- persistent flag-synced kernel --------------------------------
// bid 0..127  : layer1  (8 m-tiles x 32 rows) x (16 j-chunks x 32 cols/gate)
// bid 128..191: layer0  (4 m-tiles x 64 rows) x (16 j-chunks x 32 cols/gate)
// bid 192..199: linear  (8 m-tiles x 32 rows)
// Flags: flags[id*FSTRIDE], one writer, value = t+1 after step t.
// Steady state: L0 runs ~7 steps ahead of L1 (ring slack), so L1 polls all its
// inputs up front and runs a single fused stage+compute phase.
__global__ void __launch_bounds__(256, 1) lstm_persist(Params P) {
  __shared__ __align__(16) __bf16 sA[64 * 72 * 8];   // 73,728 B staging (L0 max)
  float* xch = (float*)sA;                           // epilogue exchange overlay

  const int bid  = blockIdx.x;
  const int tid  = threadIdx.x;
  const int lane = tid & 63;
  const int wid  = tid >> 6;        // wave = gate (layers) or col-group (linear)
  const int khi  = lane >> 5;       // k-half within a K=16 step
  const int l32  = lane & 31;
  int* FL = P.flags;

  if (bid < 128) {
    // ========== LAYER 1 : [h1_{t-1} | h0_t] @ [Wh1 | Wi1]^T — single phase =====
    const int mt1 = bid >> 4;
    const int m0  = mt1 * 32;
    const int j0  = (bid & 15) * 32;
    const int n   = wid * HH + j0 + l32;         // weight row = gate column
    v4f breg[64];                                // 256 VGPRs, pinned resident
    {
      const __bf16* Wh = P.Wh1 + (size_t)n * HH + khi * 8;
      #pragma unroll
      for (int ks = 0; ks < 32; ++ks) breg[ks]      = *(const v4f*)(Wh + ks * 16);
      const __bf16* Wi = P.Wi1 + (size_t)n * HH + khi * 8;
      #pragma unroll
      for (int ks = 0; ks < 32; ++ks) breg[32 + ks] = *(const v4f*)(Wi + ks * 16);
      #pragma unroll
      for (int i = 0; i < 64; ++i) asm volatile("" : "+v"(breg[i]));
    }
    const int er = tid & 31, ecg = tid >> 5;     // epilogue: row er, cols ecg*4..+3
    const int jc = j0 + ecg * 4;
    const v4f bI = *(const v4f*)(P.bsum1 + jc);
    const v4f bF = *(const v4f*)(P.bsum1 + HH + jc);
    const v4f bG = *(const v4f*)(P.bsum1 + 2 * HH + jc);
    const v4f bO = *(const v4f*)(P.bsum1 + 3 * HH + jc);
    float creg[4] = {0.f, 0.f, 0.f, 0.f};
    const int hsw = l32 & 7;
    const __bf16* abase = sA + (size_t)l32 * 128 * 8;

    for (int t = 0; t < TT; ++t) {
      // all inputs up front: h1_{t-1} (16 peers), h0_t (16 L0 blocks),
      // linear released h1 slot (lin done t-8 -> flag >= t-7)
      if (tid < 16)       pollOne(FL + (64 + mt1 * 16 + tid) * FSTRIDE, t);
      else if (tid < 32)  pollOne(FL + ((mt1 >> 1) * 16 + (tid - 16)) * FSTRIDE, t + 1);
      else if (tid == 32) pollOne(FL + (192 + mt1) * FSTRIDE, t - 7);
      __syncthreads();
      {  // stage h1_{t-1} -> chunks 0..63, h0_t -> chunks 64..127
        const __bf16* s1 = P.h1 + (size_t)((t + NSLOT - 1) & (NSLOT - 1)) * BBHH + (size_t)m0 * HH;
        const __bf16* s0 = P.h0 + (size_t)(t & (NSLOT - 1)) * BBHH + (size_t)m0 * HH;
        #pragma unroll
        for (int rd = 0; rd < 8; ++rd) {
          int g = rd * 256 + tid, row = g >> 6, cc = g & 63;
          const unsigned long long* p = (const unsigned long long*)(s1 + (size_t)row * HH + cc * 8);
          unsigned long long tmp[2] = { aload8(p), aload8(p + 1) };
          *(v8bf*)(sA + ((size_t)row * 128 + (cc ^ (row & 7))) * 8) = *(const v8bf*)tmp;
        }
        #pragma unroll
        for (int rd = 0; rd < 8; ++rd) {
          int g = rd * 256 + tid, row = g >> 6, cc = g & 63;
          const unsigned long long* p = (const unsigned long long*)(s0 + (size_t)row * HH + cc * 8);
          unsigned long long tmp[2] = { aload8(p), aload8(p + 1) };
          *(v8bf*)(sA + ((size_t)row * 128 + (64 + (cc ^ (row & 7)))) * 8) = *(const v8bf*)tmp;
        }
      }
      __syncthreads();
      v16f a0 = {0,0,0,0,0,0,0,0,0,0,0,0,0,0,0,0};
      v16f a1 = {0,0,0,0,0,0,0,0,0,0,0,0,0,0,0,0};
      #pragma unroll
      for (int ks = 0; ks < 64; ks += 2) {       // full K=1024 in one sweep
        v8bf af0 = *(const v8bf*)(abase + (((ks    ) * 2 + khi) ^ hsw) * 8);
        a0 = mfma32(af0, bc(breg[ks]), a0);
        v8bf af1 = *(const v8bf*)(abase + (((ks + 1) * 2 + khi) ^ hsw) * 8);
        a1 = mfma32(af1, bc(breg[ks + 1]), a1);
      }
      __syncthreads();                           // A reads done; overlay xch
      #pragma unroll
      for (int rg = 0; rg < 16; ++rg) {
        int row = (rg & 3) + 8 * (rg >> 2) + 4 * khi;   // 32x32 C/D [m74/m101]
        xch[row * XSTR + wid * 32 + l32] = a0[rg] + a1[rg];
      }
      __syncthreads();
      {
        const float* xr = xch + er * XSTR + ecg * 4;
        v4f vi = *(const v4f*)(xr);
        v4f vf = *(const v4f*)(xr + 32);
        v4f vg = *(const v4f*)(xr + 64);
        v4f vo = *(const v4f*)(xr + 96);
        unsigned long long pk = 0;
        #pragma unroll
        for (int q = 0; q < 4; ++q) {
          float cn = sigm(vf[q] + bF[q]) * creg[q] + sigm(vi[q] + bI[q]) * tanh_fast(vg[q] + bG[q]);
          creg[q] = cn;
          __bf16 hb = (__bf16)(sigm(vo[q] + bO[q]) * tanh_fast(cn));
          pk |= (unsigned long long)__builtin_bit_cast(unsigned short, hb) << (16 * q);
        }
        astore8((unsigned long long*)(P.h1 + (size_t)(t & (NSLOT - 1)) * BBHH
                                      + (size_t)(m0 + er) * HH + jc), pk);
      }
      drainAll();
      setFlag(FL + (64 + bid) * FSTRIDE, t + 1);
    }
  } else if (bid < 192) {
    // ========== LAYER 0 : [x_t | h0_{t-1}] @ [Wi0 | Wh0]^T — single 64-row pass
    const int b0 = bid - 128;
    const int mt = b0 >> 4;
    const int m0 = mt * 64;
    const int j0 = (b0 & 15) * 32;
    const int n  = wid * HH + j0 + l32;
    v4f breg[36];                                // 144 VGPRs, pinned resident
    {
      const __bf16* Wi = P.Wi0 + (size_t)n * IND + khi * 8;
      #pragma unroll
      for (int ks = 0; ks < 4; ++ks) breg[ks] = *(const v4f*)(Wi + ks * 16);
      const __bf16* Wh = P.Wh0 + (size_t)n * HH + khi * 8;
      #pragma unroll
      for (int ks = 0; ks < 32; ++ks) breg[4 + ks] = *(const v4f*)(Wh + ks * 16);
      #pragma unroll
      for (int i = 0; i < 36; ++i) asm volatile("" : "+v"(breg[i]));
    }
    const int er = tid & 31, ecg = tid >> 5;
    const int jc = j0 + ecg * 4;
    const v4f bI = *(const v4f*)(P.bsum0 + jc);
    const v4f bF = *(const v4f*)(P.bsum0 + HH + jc);
    const v4f bG = *(const v4f*)(P.bsum0 + 2 * HH + jc);
    const v4f bO = *(const v4f*)(P.bsum0 + 3 * HH + jc);
    float creg[2][4] = {{0.f,0.f,0.f,0.f},{0.f,0.f,0.f,0.f}};
    const int hsw = l32 & 7;
    const __bf16* ab0 = sA + (size_t)l32 * 72 * 8;        // row-tile 0
    const __bf16* ab1 = ab0 + (size_t)32 * 72 * 8;        // row-tile 1

    for (int t = 0; t < TT; ++t) {
      // own tile h0_{t-1} (16 peers); back-pressure: L1 consumed h0(t-8)
      if (tid < 16)      pollOne(FL + (mt * 16 + tid) * FSTRIDE, t);
      else if (tid < 48) pollOne(FL + (64 + mt * 32 + (tid - 16)) * FSTRIDE, t - 7);
      __syncthreads();
      const __bf16* h0src = P.h0 + (size_t)((t + NSLOT - 1) & (NSLOT - 1)) * BBHH;
      __bf16*       hdst  = P.h0 + (size_t)(t & (NSLOT - 1)) * BBHH;
      {  // stage x_t: 64 rows x 8 chunks (chunks 0..7; prep-written, normal loads)
        #pragma unroll
        for (int i = 0; i < 2; ++i) {
          int g = i * 256 + tid, row = g >> 3, cc = g & 7;
          const __bf16* src = P.xb + (size_t)t * BB * IND + (size_t)(m0 + row) * IND;
          v8bf v = *(const v8bf*)(src + cc * 8);
          *(v8bf*)(sA + ((size_t)row * 72 + (cc ^ (row & 7))) * 8) = v;
        }
        #pragma unroll
        for (int rd = 0; rd < 16; ++rd) {        // stage h0_{t-1}: 64 rows, chunks 8..71
          int g = rd * 256 + tid, row = g >> 6, cc = g & 63;
          const unsigned long long* p = (const unsigned long long*)
              (h0src + (size_t)(m0 + row) * HH + cc * 8);
          unsigned long long tmp[2] = { aload8(p), aload8(p + 1) };
          *(v8bf*)(sA + ((size_t)row * 72 + (8 + (cc ^ (row & 7)))) * 8) = *(const v8bf*)tmp;
        }
      }
      __syncthreads();
      v16f a00 = {0,0,0,0,0,0,0,0,0,0,0,0,0,0,0,0};
      v16f a01 = {0,0,0,0,0,0,0,0,0,0,0,0,0,0,0,0};
      v16f a10 = {0,0,0,0,0,0,0,0,0,0,0,0,0,0,0,0};
      v16f a11 = {0,0,0,0,0,0,0,0,0,0,0,0,0,0,0,0};
      #pragma unroll
      for (int ks = 0; ks < 36; ks += 2) {
        int c0 = ((ks * 2 + khi) ^ hsw) * 8, c1 = ((ks * 2 + 2 + khi) ^ hsw) * 8;
        a00 = mfma32(*(const v8bf*)(ab0 + c0), bc(breg[ks]), a00);
        a10 = mfma32(*(const v8bf*)(ab1 + c0), bc(breg[ks]), a10);
        a01 = mfma32(*(const v8bf*)(ab0 + c1), bc(breg[ks + 1]), a01);
        a11 = mfma32(*(const v8bf*)(ab1 + c1), bc(breg[ks + 1]), a11);
      }
      __syncthreads();                           // A reads done; overlay xch (64 rows)
      #pragma unroll
      for (int rg = 0; rg < 16; ++rg) {
        int row = (rg & 3) + 8 * (rg >> 2) + 4 * khi;
        xch[row * XSTR + wid * 32 + l32]        = a00[rg] + a01[rg];
        xch[(32 + row) * XSTR + wid * 32 + l32] = a10[rg] + a11[rg];
      }
      __syncthreads();
      #pragma unroll
      for (int rt = 0; rt < 2; ++rt) {
        const int row = rt * 32 + er;
        const float* xr = xch + row * XSTR + ecg * 4;
        v4f vi = *(const v4f*)(xr);
        v4f vf = *(const v4f*)(xr + 32);
        v4f vg = *(const v4f*)(xr + 64);
        v4f vo = *(const v4f*)(xr + 96);
        unsigned long long pk = 0;
        #pragma unroll
        for (int q = 0; q < 4; ++q) {
          float cn = sigm(vf[q] + bF[q]) * creg[rt][q]
                   + sigm(vi[q] + bI[q]) * tanh_fast(vg[q] + bG[q]);
          creg[rt][q] = cn;
          __bf16 hb = (__bf16)(sigm(vo[q] + bO[q]) * tanh_fast(cn));
          pk |= (unsigned long long)__builtin_bit_cast(unsigned short, hb) << (16 * q);
        }
        astore8((unsigned long long*)(hdst + (size_t)(m0 + row) * HH + jc), pk);
      }
      drainAll();
      setFlag(FL + b0 * FSTRIDE, t + 1);
    }
  } else if (bid < 200) {
    // =================== LINEAR : h1_t @ Wlin^T + blin =========================
    const int q   = bid - 192;
    const int m0  = q * 32;
    const int l16 = lane & 15, quad = lane >> 4;
    const int col = wid * 16 + l16;
    v4f breg[16];                                // 64 VGPRs, pinned resident
    {
      const __bf16* W = P.Wlin + (size_t)col * HH + quad * 8;
      #pragma unroll
      for (int kk = 0; kk < 16; ++kk) breg[kk] = *(const v4f*)(W + kk * 32);
      #pragma unroll
      for (int i = 0; i < 16; ++i) asm volatile("" : "+v"(breg[i]));
    }
    const float bb = P.blin[col];
    for (int t = 0; t < TT; ++t) {
      if (tid < 16) pollOne(FL + (64 + q * 16 + tid) * FSTRIDE, t + 1);   // h1_t
      __syncthreads();
      {  // stage h1_t rows m0..m0+31
        const __bf16* src = P.h1 + (size_t)(t & (NSLOT - 1)) * BBHH + (size_t)m0 * HH;
        #pragma unroll
        for (int rd = 0; rd < 8; ++rd) {
          int g = rd * 256 + tid, row = g >> 6, cc = g & 63;
          const unsigned long long* p = (const unsigned long long*)(src + (size_t)row * HH + cc * 8);
          unsigned long long tmp[2] = { aload8(p), aload8(p + 1) };
          *(v8bf*)(sA + ((size_t)row * 64 + (cc ^ (row & 7))) * 8) = *(const v8bf*)tmp;
        }
      }
      __syncthreads();
      v4f acc0 = {0.f,0.f,0.f,0.f}, acc1 = {0.f,0.f,0.f,0.f};
      #pragma unroll
      for (int kk = 0; kk < 16; ++kk) {
        int c8 = kk * 4 + quad;
        int r0 = l16, r1 = 16 + l16;
        v8bf af0 = *(const v8bf*)(sA + ((size_t)r0 * 64 + (c8 ^ (r0 & 7))) * 8);
        acc0 = mfma16(af0, bc(breg[kk]), acc0);
        v8bf af1 = *(const v8bf*)(sA + ((size_t)r1 * 64 + (c8 ^ (r1 & 7))) * 8);
        acc1 = mfma16(af1, bc(breg[kk]), acc1);
      }
      #pragma unroll
      for (int r = 0; r < 4; ++r) {              // 16x16 C/D: row=quad*4+r, col=l16
        int b0r = m0 + quad * 4 + r;
        P.out[(size_t)b0r * (TT * OD) + (size_t)t * OD + col] = acc0[r] + bb;
        int b1r = m0 + 16 + quad * 4 + r;
        P.out[(size_t)b1r * (TT * OD) + (size_t)t * OD + col] = acc1[r] + bb;
      }
      drainAll();                                // h1_t LDS-stage loads complete
      setFlag(FL + (192 + q) * FSTRIDE, t + 1);  // release h1 slot
    }
  }
}

// ---------------- host ----------------------------------------------------------
extern "C" void kernel_launch(void* const* d_in, const int* in_sizes, int n_in,
                              void* d_out, int out_size, void* d_ws, size_t ws_size,
                              hipStream_t stream) {
  const float* x    = (const float*)d_in[0];
  const float* Wi0  = (const float*)d_in[1];
  const float* Wh0  = (const float*)d_in[2];
  const float* bi0  = (const float*)d_in[3];
  const float* bh0  = (const float*)d_in[4];
  const float* Wi1  = (const float*)d_in[5];
  const float* Wh1  = (const float*)d_in[6];
  const float* bi1  = (const float*)d_in[7];
  const float* bh1  = (const float*)d_in[8];
  const float* Wlin = (const float*)d_in[9];
  const float* blin = (const float*)d_in[10];

  char* base = (char*)d_ws;
  size_t off = 0;
  auto take = [&](size_t nbytes) {
    void* p = base + off;
    off = (off + nbytes + 255) & ~(size_t)255;
    return p;
  };
  __bf16* xb    = (__bf16*)take(sizeof(__bf16) * (size_t)TT * BB * IND);
  __bf16* Wi0b  = (__bf16*)take(sizeof(__bf16) * 4 * HH * IND);
  __bf16* Wh0b  = (__bf16*)take(sizeof(__bf16) * 4 * HH * HH);
  __bf16* Wi1b  = (__bf16*)take(sizeof(__bf16) * 4 * HH * HH);
  __bf16* Wh1b  = (__bf16*)take(sizeof(__bf16) * 4 * HH * HH);
  __bf16* Wlinb = (__bf16*)take(sizeof(__bf16) * OD * HH);
  float*  bsum0 = (float*)take(sizeof(float) * 4 * HH);
  float*  bsum1 = (float*)take(sizeof(float) * 4 * HH);
  __bf16* h0    = (__bf16*)take(sizeof(__bf16) * NSLOT * BBHH);
  __bf16* h1    = (__bf16*)take(sizeof(__bf16) * NSLOT * BBHH);
  int*    flags = (int*)take(sizeof(int) * 200 * FSTRIDE);

  prep_kernel<<<dim3(1024), dim3(256), 0, stream>>>(
      x, Wi0, Wh0, bi0, bh0, Wi1, Wh1, bi1, bh1, Wlin,
      xb, Wi0b, Wh0b, Wi1b, Wh1b, Wlinb, bsum0, bsum1, h0, h1, flags);

  Params P;
  P.xb = xb; P.Wi0 = Wi0b; P.Wh0 = Wh0b; P.Wi1 = Wi1b; P.Wh1 = Wh1b; P.Wlin = Wlinb;
  P.bsum0 = bsum0; P.bsum1 = bsum1; P.blin = blin;
  P.h0 = h0; P.h1 = h1;
  P.flags = flags;
  P.out = (float*)d_out;

  void* kargs[] = { (void*)&P };
  hipError_t err = hipLaunchCooperativeKernel(reinterpret_cast<void*>(lstm_persist),
                                              dim3(200), dim3(256), kargs, 0, stream);
  if (err != hipSuccess) {
    // Flag protocol needs co-residency only: 200 blocks @ 1 block/CU on 256 CUs.
    lstm_persist<<<dim3(200), dim3(256), 0, stream>>>(P);
  }
}

// Round 6
// 3785.906 us; speedup vs baseline: 1.3630x; 1.3630x over previous
//
#include <hip/hip_runtime.h>
#include <hip/hip_bf16.h>

#define TT  512
#define BB  256
#define IND 64
#define HH  512
#define OD  64
#define BBHH (BB * HH)
#define NSLOT 8      // h ring depth (slot = t & 7)
#define FSTRIDE 32   // ints per flag line (128B)
#define XSTR 133     // xch row stride in floats

typedef __bf16 v8bf  __attribute__((ext_vector_type(8)));
typedef float  v4f   __attribute__((ext_vector_type(4)));
typedef float  v16f  __attribute__((ext_vector_type(16)));

struct Params {
  const __bf16 *xb, *Wi0, *Wh0, *Wi1, *Wh1, *Wlin;
  const float  *bsum0, *bsum1, *blin;
  __bf16 *h0, *h1;          // NSLOT-deep ring buffers [NSLOT][BB*HH]
  int *flags;               // per-producer: [0..63]=L0, [64..191]=L1, [192..199]=lin
  float *out;               // [BB][TT*OD]
};

__device__ __forceinline__ float sigm(float x) { return 1.f / (1.f + __expf(-x)); }
__device__ __forceinline__ float tanh_fast(float x) {
  float e = __expf(2.f * x);
  return 1.f - 2.f / (e + 1.f);
}
__device__ __forceinline__ v4f mfma16(v8bf a, v8bf b, v4f c) {
  return __builtin_amdgcn_mfma_f32_16x16x32_bf16(a, b, c, 0, 0, 0);
}
__device__ __forceinline__ v16f mfma32(v8bf a, v8bf b, v16f c) {
  return __builtin_amdgcn_mfma_f32_32x32x16_bf16(a, b, c, 0, 0, 0);
}
__device__ __forceinline__ v8bf bc(v4f x) { return __builtin_bit_cast(v8bf, x); }

// 16B LLC-coherent load (sc0 sc1 = bypass L1/L2, serviced at LLC like
// agent-scope atomics, but 2x wider than the 8B atomic-load max).
// Result NOT ready until vwait() — caller must call vwait() before use.
__device__ __forceinline__ v8bf cload16(const __bf16* p) {
  v8bf r;
  asm volatile("global_load_dwordx4 %0, %1, off sc0 sc1" : "=v"(r) : "v"(p));
  return r;
}
__device__ __forceinline__ void vwait() {
  asm volatile("s_waitcnt vmcnt(0)" ::: "memory");
}
__device__ __forceinline__ void astore8(unsigned long long* p, unsigned long long v) {
  __hip_atomic_store(p, v, __ATOMIC_RELAXED, __HIP_MEMORY_SCOPE_AGENT);
}
__device__ __forceinline__ void pollOne(const int* p, int target) {
  while (__hip_atomic_load(p, __ATOMIC_RELAXED, __HIP_MEMORY_SCOPE_AGENT) < target)
    __builtin_amdgcn_s_sleep(1);
}
__device__ __forceinline__ void drainAll() {   // h-stores complete at LLC
  asm volatile("s_waitcnt vmcnt(0)" ::: "memory");
  __syncthreads();
}
__device__ __forceinline__ void setFlag(int* f, int v) {
  if (threadIdx.x == 0)
    __hip_atomic_store(f, v, __ATOMIC_RELAXED, __HIP_MEMORY_SCOPE_AGENT);
}

// ---------------- prep: fp32 -> bf16, combined biases, zero states/flags -------
__global__ void __launch_bounds__(256) prep_kernel(
    const float* x, const float* Wi0, const float* Wh0, const float* bi0, const float* bh0,
    const float* Wi1, const float* Wh1, const float* bi1, const float* bh1, const float* Wlin,
    __bf16* xb, __bf16* Wi0b, __bf16* Wh0b, __bf16* Wi1b, __bf16* Wh1b, __bf16* Wlinb,
    float* bsum0, float* bsum1, __bf16* h0, __bf16* h1, int* flags) {
  size_t tid = (size_t)blockIdx.x * blockDim.x + threadIdx.x;
  size_t np  = (size_t)gridDim.x * blockDim.x;
  for (size_t i = tid; i < (size_t)TT * BB * IND; i += np) xb[i]    = (__bf16)x[i];
  for (size_t i = tid; i < (size_t)4 * HH * IND;  i += np) Wi0b[i]  = (__bf16)Wi0[i];
  for (size_t i = tid; i < (size_t)4 * HH * HH;   i += np) Wh0b[i]  = (__bf16)Wh0[i];
  for (size_t i = tid; i < (size_t)4 * HH * HH;   i += np) Wi1b[i]  = (__bf16)Wi1[i];
  for (size_t i = tid; i < (size_t)4 * HH * HH;   i += np) Wh1b[i]  = (__bf16)Wh1[i];
  for (size_t i = tid; i < (size_t)OD * HH;       i += np) Wlinb[i] = (__bf16)Wlin[i];
  for (size_t i = tid; i < (size_t)4 * HH; i += np) {
    bsum0[i] = bi0[i] + bh0[i];
    bsum1[i] = bi1[i] + bh1[i];
  }
  for (size_t i = tid; i < (size_t)NSLOT * BBHH; i += np) { h0[i] = (__bf16)0.f; h1[i] = (__bf16)0.f; }
  for (size_t i = tid; i < (size_t)200 * FSTRIDE; i += np) flags[i] = 0;
}

// ---------------- persistent flag-synced kernel --------------------------------
// bid 0..127  : layer1  (8 m-tiles x 32 rows) x (16 j-chunks x 32 cols/gate)
// bid 128..191: layer0  (4 m-tiles x 64 rows) x (16 j-chunks x 32 cols/gate)
// bid 192..199: linear  (8 m-tiles x 32 rows)
// Flags: flags[id*FSTRIDE], one writer, value = t+1 after step t.
__global__ void __launch_bounds__(256, 1) lstm_persist(Params P) {
  __shared__ __align__(16) __bf16 sA[32 * 128 * 8];  // 65,536 B staging (L1 max)
  __shared__ __align__(16) float  xch[32 * XSTR];    // 17,024 B gate exchange

  const int bid  = blockIdx.x;
  const int tid  = threadIdx.x;
  const int lane = tid & 63;
  const int wid  = tid >> 6;        // wave = gate (layers) or col-group (linear)
  const int khi  = lane >> 5;       // k-half within a K=16 step
  const int l32  = lane & 31;
  int* FL = P.flags;

  if (bid < 128) {
    // ========== LAYER 1 : [h1_{t-1} | h0_t] @ [Wh1 | Wi1]^T — single phase =====
    const int mt1 = bid >> 4;
    const int m0  = mt1 * 32;
    const int j0  = (bid & 15) * 32;
    const int n   = wid * HH + j0 + l32;         // weight row = gate column
    v4f breg[64];                                // 256 regs (AGPR-resident)
    {
      const __bf16* Wh = P.Wh1 + (size_t)n * HH + khi * 8;
      #pragma unroll
      for (int ks = 0; ks < 32; ++ks) breg[ks]      = *(const v4f*)(Wh + ks * 16);
      const __bf16* Wi = P.Wi1 + (size_t)n * HH + khi * 8;
      #pragma unroll
      for (int ks = 0; ks < 32; ++ks) breg[32 + ks] = *(const v4f*)(Wi + ks * 16);
      #pragma unroll
      for (int i = 0; i < 64; ++i) asm volatile("" : "+v"(breg[i]));
    }
    const int er = tid & 31, ecg = tid >> 5;     // epilogue: row er, cols ecg*4..+3
    const int jc = j0 + ecg * 4;
    const v4f bI = *(const v4f*)(P.bsum1 + jc);
    const v4f bF = *(const v4f*)(P.bsum1 + HH + jc);
    const v4f bG = *(const v4f*)(P.bsum1 + 2 * HH + jc);
    const v4f bO = *(const v4f*)(P.bsum1 + 3 * HH + jc);
    float creg[4] = {0.f, 0.f, 0.f, 0.f};
    const int hsw = l32 & 7;
    const __bf16* abase = sA + (size_t)l32 * 128 * 8;

    for (int t = 0; t < TT; ++t) {
      if (tid < 16)       pollOne(FL + (64 + mt1 * 16 + tid) * FSTRIDE, t);        // h1_{t-1}
      else if (tid < 32)  pollOne(FL + ((mt1 >> 1) * 16 + (tid - 16)) * FSTRIDE, t + 1); // h0_t
      else if (tid == 32) pollOne(FL + (192 + mt1) * FSTRIDE, t - 7);              // slot free
      __syncthreads();
      {  // stage h1_{t-1} -> chunks 0..63, h0_t -> chunks 64..127 (16B coherent)
        const __bf16* s1 = P.h1 + (size_t)((t + NSLOT - 1) & (NSLOT - 1)) * BBHH + (size_t)m0 * HH;
        const __bf16* s0 = P.h0 + (size_t)(t & (NSLOT - 1)) * BBHH + (size_t)m0 * HH;
        v8bf t1[8], t0[8];
        #pragma unroll
        for (int rd = 0; rd < 8; ++rd) {
          int g = rd * 256 + tid, row = g >> 6, cc = g & 63;
          t1[rd] = cload16(s1 + (size_t)row * HH + cc * 8);
          t0[rd] = cload16(s0 + (size_t)row * HH + cc * 8);
        }
        vwait();
        #pragma unroll
        for (int rd = 0; rd < 8; ++rd) {
          int g = rd * 256 + tid, row = g >> 6, cc = g & 63;
          *(v8bf*)(sA + ((size_t)row * 128 + (cc ^ (row & 7))) * 8)        = t1[rd];
          *(v8bf*)(sA + ((size_t)row * 128 + (64 + (cc ^ (row & 7)))) * 8) = t0[rd];
        }
      }
      __syncthreads();
      v16f a0 = {0,0,0,0,0,0,0,0,0,0,0,0,0,0,0,0};
      v16f a1 = {0,0,0,0,0,0,0,0,0,0,0,0,0,0,0,0};
      #pragma unroll
      for (int ks = 0; ks < 64; ks += 2) {       // full K=1024 in one sweep
        v8bf af0 = *(const v8bf*)(abase + (((ks    ) * 2 + khi) ^ hsw) * 8);
        a0 = mfma32(af0, bc(breg[ks]), a0);
        v8bf af1 = *(const v8bf*)(abase + (((ks + 1) * 2 + khi) ^ hsw) * 8);
        a1 = mfma32(af1, bc(breg[ks + 1]), a1);
      }
      // xch is a separate region: no barrier needed between MFMA reads and this
      #pragma unroll
      for (int rg = 0; rg < 16; ++rg) {
        int row = (rg & 3) + 8 * (rg >> 2) + 4 * khi;   // 32x32 C/D [m74/m101]
        xch[row * XSTR + wid * 32 + l32] = a0[rg] + a1[rg];
      }
      __syncthreads();
      {
        const float* xr = xch + er * XSTR + ecg * 4;
        v4f vi = *(const v4f*)(xr);
        v4f vf = *(const v4f*)(xr + 32);
        v4f vg = *(const v4f*)(xr + 64);
        v4f vo = *(const v4f*)(xr + 96);
        unsigned long long pk = 0;
        #pragma unroll
        for (int q = 0; q < 4; ++q) {
          float cn = sigm(vf[q] + bF[q]) * creg[q] + sigm(vi[q] + bI[q]) * tanh_fast(vg[q] + bG[q]);
          creg[q] = cn;
          __bf16 hb = (__bf16)(sigm(vo[q] + bO[q]) * tanh_fast(cn));
          pk |= (unsigned long long)__builtin_bit_cast(unsigned short, hb) << (16 * q);
        }
        astore8((unsigned long long*)(P.h1 + (size_t)(t & (NSLOT - 1)) * BBHH
                                      + (size_t)(m0 + er) * HH + jc), pk);
      }
      drainAll();
      setFlag(FL + (64 + bid) * FSTRIDE, t + 1);
    }
  } else if (bid < 192) {
    // ========== LAYER 0 : [x_t | h0_{t-1}] @ [Wi0 | Wh0]^T — two 32-row passes =
    const int b0 = bid - 128;
    const int mt = b0 >> 4;
    const int m0 = mt * 64;
    const int j0 = (b0 & 15) * 32;
    const int n  = wid * HH + j0 + l32;
    v4f breg[36];                                // 144 regs, pinned resident
    {
      const __bf16* Wi = P.Wi0 + (size_t)n * IND + khi * 8;
      #pragma unroll
      for (int ks = 0; ks < 4; ++ks) breg[ks] = *(const v4f*)(Wi + ks * 16);
      const __bf16* Wh = P.Wh0 + (size_t)n * HH + khi * 8;
      #pragma unroll
      for (int ks = 0; ks < 32; ++ks) breg[4 + ks] = *(const v4f*)(Wh + ks * 16);
      #pragma unroll
      for (int i = 0; i < 36; ++i) asm volatile("" : "+v"(breg[i]));
    }
    const int er = tid & 31, ecg = tid >> 5;
    const int jc = j0 + ecg * 4;
    const v4f bI = *(const v4f*)(P.bsum0 + jc);
    const v4f bF = *(const v4f*)(P.bsum0 + HH + jc);
    const v4f bG = *(const v4f*)(P.bsum0 + 2 * HH + jc);
    const v4f bO = *(const v4f*)(P.bsum0 + 3 * HH + jc);
    float creg[2][4] = {{0.f,0.f,0.f,0.f},{0.f,0.f,0.f,0.f}};
    const int hsw = l32 & 7;
    const __bf16* abase = sA + (size_t)l32 * 72 * 8;

    for (int t = 0; t < TT; ++t) {
      if (tid < 16)      pollOne(FL + (mt * 16 + tid) * FSTRIDE, t);               // h0_{t-1}
      else if (tid < 48) pollOne(FL + (64 + mt * 32 + (tid - 16)) * FSTRIDE, t - 7); // slot free
      __syncthreads();
      const __bf16* h0src = P.h0 + (size_t)((t + NSLOT - 1) & (NSLOT - 1)) * BBHH;
      __bf16*       hdst  = P.h0 + (size_t)(t & (NSLOT - 1)) * BBHH;
      #pragma unroll 1
      for (int rt = 0; rt < 2; ++rt) {
        if (rt) __syncthreads();                 // rt0 mfma reads + xch reads done
        {  // stage x_t (normal loads; prep-written) + h0_{t-1} (16B coherent)
          v8bf th[8];
          int xrow = tid >> 3, xcc = tid & 7;
          v8bf tx = *(const v8bf*)(P.xb + (size_t)t * BB * IND
                                   + (size_t)(m0 + rt * 32 + xrow) * IND + xcc * 8);
          #pragma unroll
          for (int rd = 0; rd < 8; ++rd) {
            int g = rd * 256 + tid, row = g >> 6, cc = g & 63;
            th[rd] = cload16(h0src + (size_t)(m0 + rt * 32 + row) * HH + cc * 8);
          }
          vwait();
          *(v8bf*)(sA + ((size_t)xrow * 72 + (xcc ^ (xrow & 7))) * 8) = tx;
          #pragma unroll
          for (int rd = 0; rd < 8; ++rd) {
            int g = rd * 256 + tid, row = g >> 6, cc = g & 63;
            *(v8bf*)(sA + ((size_t)row * 72 + (8 + (cc ^ (row & 7)))) * 8) = th[rd];
          }
        }
        __syncthreads();
        v16f a0 = {0,0,0,0,0,0,0,0,0,0,0,0,0,0,0,0};
        v16f a1 = {0,0,0,0,0,0,0,0,0,0,0,0,0,0,0,0};
        #pragma unroll
        for (int ks = 0; ks < 36; ks += 2) {
          v8bf af0 = *(const v8bf*)(abase + ((ks * 2 + khi) ^ hsw) * 8);
          a0 = mfma32(af0, bc(breg[ks]), a0);
          v8bf af1 = *(const v8bf*)(abase + ((ks * 2 + 2 + khi) ^ hsw) * 8);
          a1 = mfma32(af1, bc(breg[ks + 1]), a1);
        }
        #pragma unroll
        for (int rg = 0; rg < 16; ++rg) {
          int row = (rg & 3) + 8 * (rg >> 2) + 4 * khi;
          xch[row * XSTR + wid * 32 + l32] = a0[rg] + a1[rg];
        }
        __syncthreads();
        {
          const float* xr = xch + er * XSTR + ecg * 4;
          v4f vi = *(const v4f*)(xr);
          v4f vf = *(const v4f*)(xr + 32);
          v4f vg = *(const v4f*)(xr + 64);
          v4f vo = *(const v4f*)(xr + 96);
          unsigned long long pk = 0;
          #pragma unroll
          for (int q = 0; q < 4; ++q) {
            float cn = sigm(vf[q] + bF[q]) * creg[rt][q]
                     + sigm(vi[q] + bI[q]) * tanh_fast(vg[q] + bG[q]);
            creg[rt][q] = cn;
            __bf16 hb = (__bf16)(sigm(vo[q] + bO[q]) * tanh_fast(cn));
            pk |= (unsigned long long)__builtin_bit_cast(unsigned short, hb) << (16 * q);
          }
          astore8((unsigned long long*)(hdst + (size_t)(m0 + rt * 32 + er) * HH + jc), pk);
        }
      }
      drainAll();
      setFlag(FL + b0 * FSTRIDE, t + 1);
    }
  } else if (bid < 200) {
    // =================== LINEAR : h1_t @ Wlin^T + blin =========================
    const int q   = bid - 192;
    const int m0  = q * 32;
    const int l16 = lane & 15, quad = lane >> 4;
    const int col = wid * 16 + l16;
    v4f breg[16];                                // 64 regs, pinned resident
    {
      const __bf16* W = P.Wlin + (size_t)col * HH + quad * 8;
      #pragma unroll
      for (int kk = 0; kk < 16; ++kk) breg[kk] = *(const v4f*)(W + kk * 32);
      #pragma unroll
      for (int i = 0; i < 16; ++i) asm volatile("" : "+v"(breg[i]));
    }
    const float bb = P.blin[col];
    for (int t = 0; t < TT; ++t) {
      if (tid < 16) pollOne(FL + (64 + q * 16 + tid) * FSTRIDE, t + 1);   // h1_t
      __syncthreads();
      {  // stage h1_t rows m0..m0+31 (16B coherent)
        const __bf16* src = P.h1 + (size_t)(t & (NSLOT - 1)) * BBHH + (size_t)m0 * HH;
        v8bf th[8];
        #pragma unroll
        for (int rd = 0; rd < 8; ++rd) {
          int g = rd * 256 + tid, row = g >> 6, cc = g & 63;
          th[rd] = cload16(src + (size_t)row * HH + cc * 8);
        }
        vwait();
        #pragma unroll
        for (int rd = 0; rd < 8; ++rd) {
          int g = rd * 256 + tid, row = g >> 6, cc = g & 63;
          *(v8bf*)(sA + ((size_t)row * 64 + (cc ^ (row & 7))) * 8) = th[rd];
        }
      }
      __syncthreads();
      // h1 reads are complete (vwait) -> release the slot NOW, off critical path
      setFlag(FL + (192 + q) * FSTRIDE, t + 1);
      v4f acc0 = {0.f,0.f,0.f,0.f}, acc1 = {0.f,0.f,0.f,0.f};
      #pragma unroll
      for (int kk = 0; kk < 16; ++kk) {
        int c8 = kk * 4 + quad;
        int r0 = l16, r1 = 16 + l16;
        v8bf af0 = *(const v8bf*)(sA + ((size_t)r0 * 64 + (c8 ^ (r0 & 7))) * 8);
        acc0 = mfma16(af0, bc(breg[kk]), acc0);
        v8bf af1 = *(const v8bf*)(sA + ((size_t)r1 * 64 + (c8 ^ (r1 & 7))) * 8);
        acc1 = mfma16(af1, bc(breg[kk]), acc1);
      }
      #pragma unroll
      for (int r = 0; r < 4; ++r) {              // 16x16 C/D: row=quad*4+r, col=l16
        int b0r = m0 + quad * 4 + r;
        P.out[(size_t)b0r * (TT * OD) + (size_t)t * OD + col] = acc0[r] + bb;
        int b1r = m0 + 16 + quad * 4 + r;
        P.out[(size_t)b1r * (TT * OD) + (size_t)t * OD + col] = acc1[r] + bb;
      }
      // no drain: out has no consumers; next-iter barrier orders sA reuse
    }
  }
}

// ---------------- host ----------------------------------------------------------
extern "C" void kernel_launch(void* const* d_in, const int* in_sizes, int n_in,
                              void* d_out, int out_size, void* d_ws, size_t ws_size,
                              hipStream_t stream) {
  const float* x    = (const float*)d_in[0];
  const float* Wi0  = (const float*)d_in[1];
  const float* Wh0  = (const float*)d_in[2];
  const float* bi0  = (const float*)d_in[3];
  const float* bh0  = (const float*)d_in[4];
  const float* Wi1  = (const float*)d_in[5];
  const float* Wh1  = (const float*)d_in[6];
  const float* bi1  = (const float*)d_in[7];
  const float* bh1  = (const float*)d_in[8];
  const float* Wlin = (const float*)d_in[9];
  const float* blin = (const float*)d_in[10];

  char* base = (char*)d_ws;
  size_t off = 0;
  auto take = [&](size_t nbytes) {
    void* p = base + off;
    off = (off + nbytes + 255) & ~(size_t)255;
    return p;
  };
  __bf16* xb    = (__bf16*)take(sizeof(__bf16) * (size_t)TT * BB * IND);
  __bf16* Wi0b  = (__bf16*)take(sizeof(__bf16) * 4 * HH * IND);
  __bf16* Wh0b  = (__bf16*)take(sizeof(__bf16) * 4 * HH * HH);
  __bf16* Wi1b  = (__bf16*)take(sizeof(__bf16) * 4 * HH * HH);
  __bf16* Wh1b  = (__bf16*)take(sizeof(__bf16) * 4 * HH * HH);
  __bf16* Wlinb = (__bf16*)take(sizeof(__bf16) * OD * HH);
  float*  bsum0 = (float*)take(sizeof(float) * 4 * HH);
  float*  bsum1 = (float*)take(sizeof(float) * 4 * HH);
  __bf16* h0    = (__bf16*)take(sizeof(__bf16) * NSLOT * BBHH);
  __bf16* h1    = (__bf16*)take(sizeof(__bf16) * NSLOT * BBHH);
  int*    flags = (int*)take(sizeof(int) * 200 * FSTRIDE);

  prep_kernel<<<dim3(1024), dim3(256), 0, stream>>>(
      x, Wi0, Wh0, bi0, bh0, Wi1, Wh1, bi1, bh1, Wlin,
      xb, Wi0b, Wh0b, Wi1b, Wh1b, Wlinb, bsum0, bsum1, h0, h1, flags);

  Params P;
  P.xb = xb; P.Wi0 = Wi0b; P.Wh0 = Wh0b; P.Wi1 = Wi1b; P.Wh1 = Wh1b; P.Wlin = Wlinb;
  P.bsum0 = bsum0; P.bsum1 = bsum1; P.blin = blin;
  P.h0 = h0; P.h1 = h1;
  P.flags = flags;
  P.out = (float*)d_out;

  void* kargs[] = { (void*)&P };
  hipError_t err = hipLaunchCooperativeKernel(reinterpret_cast<void*>(lstm_persist),
                                              dim3(200), dim3(256), kargs, 0, stream);
  if (err != hipSuccess) {
    // Flag protocol needs co-residency only: 200 blocks @ 1 block/CU on 256 CUs.
    lstm_persist<<<dim3(200), dim3(256), 0, stream>>>(P);
  }
}